// Round 4
// baseline (355.611 us; speedup 1.0000x reference)
//
#include <hip/hip_runtime.h>

#define T_TOK 2048
#define DDIM  1024
#define EEXP  8
#define FDIM  2048

typedef __attribute__((ext_vector_type(8))) short bf16x8;
typedef __attribute__((ext_vector_type(4))) float f32x4;
typedef __attribute__((ext_vector_type(4))) unsigned short u16x4;

__device__ __forceinline__ unsigned short f2bf(float f) {
  union { float f; unsigned int u; } v; v.f = f;
  unsigned int r = v.u + 0x7FFF + ((v.u >> 16) & 1);   // RNE
  return (unsigned short)(r >> 16);
}
__device__ __forceinline__ float gelu_tanh(float x) {
  const float c = 0.7978845608028654f;  // sqrt(2/pi)
  float t = c * (x + 0.044715f * x * x * x);
  return 0.5f * x * (1.0f + tanhf(t));
}
__device__ __forceinline__ void gload_lds16(const void* g, void* lds) {
  __builtin_amdgcn_global_load_lds(
      (const __attribute__((address_space(1))) void*)g,
      (__attribute__((address_space(3))) void*)lds, 16, 0, 0);
}

// ---------------- Router (+ fused x -> bf16 convert) ------------------------
__global__ __launch_bounds__(256)
void router_kernel(const float* __restrict__ x, const float* __restrict__ Wr,
                   const float* __restrict__ br, float* __restrict__ combine,
                   unsigned short* __restrict__ xbf) {
  int t = blockIdx.x;
  int tid = threadIdx.x;
  float acc[EEXP];
#pragma unroll
  for (int e = 0; e < EEXP; ++e) acc[e] = 0.f;
  const float* xr = x + (size_t)t * DDIM;
  unsigned short* xbr = xbf + (size_t)t * DDIM;
  for (int d = tid; d < DDIM; d += 256) {
    float xv = xr[d];
    xbr[d] = f2bf(xv);
    const float* w = Wr + d * EEXP;
#pragma unroll
    for (int e = 0; e < EEXP; ++e) acc[e] += xv * w[e];
  }
#pragma unroll
  for (int e = 0; e < EEXP; ++e)
    for (int off = 32; off > 0; off >>= 1) acc[e] += __shfl_down(acc[e], off);
  __shared__ float red[4][EEXP];
  int wave = tid >> 6, lane = tid & 63;
  if (lane == 0)
#pragma unroll
    for (int e = 0; e < EEXP; ++e) red[wave][e] = acc[e];
  __syncthreads();
  if (tid == 0) {
    float l[EEXP];
#pragma unroll
    for (int e = 0; e < EEXP; ++e)
      l[e] = red[0][e] + red[1][e] + red[2][e] + red[3][e] + br[e];
    int i0 = 0;
    for (int e = 1; e < EEXP; ++e) if (l[e] > l[i0]) i0 = e;
    int i1 = -1;
    for (int e = 0; e < EEXP; ++e) {
      if (e == i0) continue;
      if (i1 < 0 || l[e] > l[i1]) i1 = e;
    }
    float m = l[0];
    for (int e = 1; e < EEXP; ++e) m = fmaxf(m, l[e]);
    float p[EEXP], s = 0.f;
#pragma unroll
    for (int e = 0; e < EEXP; ++e) { p[e] = __expf(l[e] - m); s += p[e]; }
    float inv = 1.0f / s;
#pragma unroll
    for (int e = 0; e < EEXP; ++e)
      combine[t * EEXP + e] = (e == i0 || e == i1) ? p[e] * inv : 0.0f;
  }
}

// ---------------- Compaction: per-expert token lists + prefix ---------------
__global__ __launch_bounds__(512)
void compact_kernel(const float* __restrict__ combine, int* __restrict__ idx,
                    int* __restrict__ meta) {
  int e = threadIdx.x >> 6, lane = threadIdx.x & 63;
  int cnt = 0;
  for (int t0 = 0; t0 < T_TOK; t0 += 64) {
    int t = t0 + lane;
    bool f = combine[t * EEXP + e] != 0.0f;
    unsigned long long m = __ballot(f);
    if (f) idx[e * T_TOK + cnt + __popcll(m & ((1ull << lane) - 1))] = t;
    cnt += __popcll(m);
  }
  __shared__ int sc[EEXP];
  if (lane == 0) sc[e] = cnt;
  __syncthreads();
  if (threadIdx.x == 0) {
    int b = 0;
    for (int i = 0; i < EEXP; ++i) { meta[i] = sc[i]; meta[8 + i] = b; b += sc[i]; }
    meta[16] = b;
  }
}

// ---------------- Weight transpose+convert: fp32 [R][C] -> bf16 [C][R] ------
__global__ __launch_bounds__(256)
void wconv_kernel(const float* __restrict__ W1, const float* __restrict__ W2,
                  unsigned short* __restrict__ W1t, unsigned short* __restrict__ W2t) {
  __shared__ float tile[32][33];
  int z = blockIdx.z;
  const float* in; unsigned short* out; int R, C;
  if (z < 8) { in = W1 + (size_t)z * DDIM * FDIM; out = W1t + (size_t)z * DDIM * FDIM; R = DDIM; C = FDIM; }
  else       { in = W2 + (size_t)(z - 8) * DDIM * FDIM; out = W2t + (size_t)(z - 8) * DDIM * FDIM; R = FDIM; C = DDIM; }
  int tilesC = C >> 5;
  int tr = blockIdx.x / tilesC, tc = blockIdx.x % tilesC;
  int r0 = tr << 5, c0 = tc << 5;
  int t = threadIdx.x;
  int lr = t >> 3, lc4 = (t & 7) << 2;
  const float4 v = *(const float4*)(in + (size_t)(r0 + lr) * C + c0 + lc4);
  tile[lr][lc4 + 0] = v.x; tile[lr][lc4 + 1] = v.y;
  tile[lr][lc4 + 2] = v.z; tile[lr][lc4 + 3] = v.w;
  __syncthreads();
  u16x4 o;
  o[0] = f2bf(tile[lc4 + 0][lr]);
  o[1] = f2bf(tile[lc4 + 1][lr]);
  o[2] = f2bf(tile[lc4 + 2][lr]);
  o[3] = f2bf(tile[lc4 + 3][lr]);
  *(u16x4*)(out + (size_t)(c0 + lr) * R + r0 + lc4) = o;
}

// ---------------- Compacted gathered GEMM, dbuf pipeline, XCD swizzle -------
// EPI 0: A = xbf gathered via idx (K=1024); Hc[base+local] = gelu(A@B^T + b1)
// EPI 1: A = Hc slots (K=2048, split-K 2x1024); accum[tok] += c*(A@B^T [+ b2])
template<int EPI>
__global__ __launch_bounds__(256)
void gemm_kernel(const unsigned short* __restrict__ A,
                 const unsigned short* __restrict__ Ball,
                 const float* __restrict__ ball,
                 const float* __restrict__ combine,
                 const int* __restrict__ idx,
                 const int* __restrict__ meta,
                 unsigned short* __restrict__ Hc,
                 float* __restrict__ accum) {
  constexpr int KF = (EPI == 0) ? DDIM : FDIM;   // full K of A rows / B rows
  constexpr int N  = (EPI == 0) ? FDIM : DDIM;
  constexpr int NT = 16;                          // K-iters of 64 (split-K for EPI1)
  __shared__ unsigned short Asub[2 * 128 * 64];   // 2 x 16KB, swizzled 128B rows
  __shared__ unsigned short Bsub[2 * 128 * 64];

  // XCD-coherent decode: id = a*128 + mtile*8 + b ; ne = a*8+b = nsl + 16*e.
  // id%8 = b = nsl%8 -> all m-tiles of one (e, n-slot) land on the same XCD.
  int id = blockIdx.x;
  int a = id >> 7, rem = id & 127;
  int mtile = rem >> 3, b = rem & 7;
  int ne = a * 8 + b;
  int nsl = ne & 15, e = ne >> 4;
  int ntile, kbeg;
  if (EPI == 0) { ntile = nsl; kbeg = 0; }
  else          { ntile = nsl & 7; kbeg = (nsl >> 3) * 1024; }

  int cnt = meta[e];
  int m0 = mtile << 7;
  if (m0 >= cnt) return;
  int base = meta[8 + e];
  const unsigned short* B = Ball + (size_t)e * KF * N;
  const float* bias = ball + (size_t)e * N;
  int n0 = ntile << 7;
  int tid = threadIdx.x, wave = tid >> 6, lane = tid & 63;
  int wm = wave >> 1, wn = wave & 1;
  int lr = lane & 15, lk = lane >> 4;

  // staging geometry (loop-invariant per lane)
  int arow[4], brow[4], scol[4];
#pragma unroll
  for (int i = 0; i < 4; ++i) {
    int phys = i * 4096 + wave * 1024 + lane * 16;
    int row = phys >> 7;
    int lc = (phys & 127) ^ ((row & 7) << 4);    // involution swizzle (bytes)
    scol[i] = lc >> 1;
    int lrow = min(m0 + row, cnt - 1);           // clamp ragged tail
    arow[i] = (EPI == 0) ? idx[e * T_TOK + lrow] : (base + lrow);
    brow[i] = n0 + row;
  }

  auto stage = [&](int buf, int kt) {
#pragma unroll
    for (int i = 0; i < 4; ++i) {
      gload_lds16(A + (size_t)arow[i] * KF + kt + scol[i],
                  (char*)Asub + buf * 16384 + i * 4096 + wave * 1024);
      gload_lds16(B + (size_t)brow[i] * KF + kt + scol[i],
                  (char*)Bsub + buf * 16384 + i * 4096 + wave * 1024);
    }
  };

  f32x4 acc[4][4] = {};
  stage(0, kbeg);
  __syncthreads();
  int cur = 0;
  for (int t = 0; t < NT; ++t) {
    if (t + 1 < NT) stage(cur ^ 1, kbeg + (t + 1) * 64);   // prefetch in flight
#pragma unroll
    for (int ks = 0; ks < 2; ++ks) {
      bf16x8 af[4], bf_[4];
#pragma unroll
      for (int m = 0; m < 4; ++m) {
        int row = wm * 64 + m * 16 + lr;
        int cb = (ks * 64 + lk * 16) ^ ((row & 7) << 4);
        af[m] = *(const bf16x8*)((const char*)Asub + cur * 16384 + row * 128 + cb);
      }
#pragma unroll
      for (int n = 0; n < 4; ++n) {
        int row = wn * 64 + n * 16 + lr;
        int cb = (ks * 64 + lk * 16) ^ ((row & 7) << 4);
        bf_[n] = *(const bf16x8*)((const char*)Bsub + cur * 16384 + row * 128 + cb);
      }
#pragma unroll
      for (int m = 0; m < 4; ++m)
#pragma unroll
        for (int n = 0; n < 4; ++n)
          acc[m][n] = __builtin_amdgcn_mfma_f32_16x16x32_bf16(af[m], bf_[n], acc[m][n], 0, 0, 0);
    }
    __syncthreads();   // drains vmcnt(0): prefetched tile ready; buf readers done
    cur ^= 1;
  }

  if (EPI == 0) {
#pragma unroll
    for (int m = 0; m < 4; ++m) {
      int lbase = m0 + wm * 64 + m * 16 + lk * 4;
#pragma unroll
      for (int n = 0; n < 4; ++n) {
        int col = n0 + wn * 64 + n * 16 + lr;
        float bv = bias[col];
#pragma unroll
        for (int r = 0; r < 4; ++r) {
          int local = lbase + r;
          if (local < cnt)
            Hc[(size_t)(base + local) * N + col] = f2bf(gelu_tanh(acc[m][n][r] + bv));
        }
      }
    }
  } else {
    bool addb = (kbeg == 0);
#pragma unroll
    for (int m = 0; m < 4; ++m) {
      int lbase = m0 + wm * 64 + m * 16 + lk * 4;
#pragma unroll
      for (int r = 0; r < 4; ++r) {
        int local = lbase + r;
        if (local < cnt) {
          int tok = idx[e * T_TOK + local];
          float c = combine[tok * EEXP + e];
#pragma unroll
          for (int n = 0; n < 4; ++n) {
            int col = n0 + wn * 64 + n * 16 + lr;
            float v = acc[m][n][r] + (addb ? bias[col] : 0.0f);
            atomicAdd(&accum[(size_t)tok * N + col], c * v);
          }
        }
      }
    }
  }
}

// ---------------- Residual + LayerNorm --------------------------------------
__global__ __launch_bounds__(256)
void ln_kernel(const float* __restrict__ x, const float* __restrict__ accum,
               const float* __restrict__ gamma, const float* __restrict__ beta,
               float* __restrict__ out) {
  int r = blockIdx.x, tid = threadIdx.x;
  size_t base = (size_t)r * DDIM + tid * 4;
  float4 xv = *(const float4*)(x + base);
  float4 av = *(const float4*)(accum + base);
  float y[4] = { xv.x + av.x, xv.y + av.y, xv.z + av.z, xv.w + av.w };
  float s = y[0] + y[1] + y[2] + y[3];
  float s2 = y[0] * y[0] + y[1] * y[1] + y[2] * y[2] + y[3] * y[3];
  for (int off = 32; off > 0; off >>= 1) {
    s += __shfl_down(s, off);
    s2 += __shfl_down(s2, off);
  }
  __shared__ float rs[4], rs2[4];
  int wave = tid >> 6, lane = tid & 63;
  if (lane == 0) { rs[wave] = s; rs2[wave] = s2; }
  __syncthreads();
  float ts = rs[0] + rs[1] + rs[2] + rs[3];
  float ts2 = rs2[0] + rs2[1] + rs2[2] + rs2[3];
  float mu = ts * (1.0f / DDIM);
  float var = ts2 * (1.0f / DDIM) - mu * mu;
  float inv = rsqrtf(var + 1e-5f);
  float4 gv = *(const float4*)(gamma + tid * 4);
  float4 bv = *(const float4*)(beta + tid * 4);
  float4 o;
  o.x = (y[0] - mu) * inv * gv.x + bv.x;
  o.y = (y[1] - mu) * inv * gv.y + bv.y;
  o.z = (y[2] - mu) * inv * gv.z + bv.z;
  o.w = (y[3] - mu) * inv * gv.w + bv.w;
  *(float4*)(out + base) = o;
}

// ================= FALLBACK (round-1 proven path, small ws) =================
#define BM 128
#define BN 128
#define BK 32
#define LDT 40

__global__ __launch_bounds__(256)
void g1_old(const float* __restrict__ X, const float* __restrict__ W1,
            const float* __restrict__ b1, unsigned short* __restrict__ H) {
  __shared__ unsigned short As[BM][LDT];
  __shared__ unsigned short Bs[BN][LDT];
  int tid = threadIdx.x;
  int trow0 = blockIdx.y * BM, ncol0 = blockIdx.x * BN;
  int wave = tid >> 6, lane = tid & 63;
  int wm = wave >> 1, wn = wave & 1;
  int lr = lane & 15, lk = lane >> 4;
  f32x4 acc[4][4] = {};
  for (int kt = 0; kt < DDIM; kt += BK) {
#pragma unroll
    for (int it = 0; it < 4; ++it) {
      int i = tid + it * 256;
      int row = i >> 3, c4 = (i & 7) << 2;
      const float4 v = *(const float4*)(X + (size_t)(trow0 + row) * DDIM + kt + c4);
      uint2 p;
      p.x = (unsigned int)f2bf(v.x) | ((unsigned int)f2bf(v.y) << 16);
      p.y = (unsigned int)f2bf(v.z) | ((unsigned int)f2bf(v.w) << 16);
      *(uint2*)&As[row][c4] = p;
    }
#pragma unroll
    for (int it = 0; it < 4; ++it) {
      int i = tid + it * 256;
      int r = i >> 5, c4 = (i & 31) << 2;
      const float4 v = *(const float4*)(W1 + (size_t)(kt + r) * FDIM + ncol0 + c4);
      Bs[c4 + 0][r] = f2bf(v.x); Bs[c4 + 1][r] = f2bf(v.y);
      Bs[c4 + 2][r] = f2bf(v.z); Bs[c4 + 3][r] = f2bf(v.w);
    }
    __syncthreads();
    bf16x8 af[4], bfr[4];
#pragma unroll
    for (int m = 0; m < 4; ++m) af[m] = *(const bf16x8*)&As[wm * 64 + m * 16 + lr][lk * 8];
#pragma unroll
    for (int n = 0; n < 4; ++n) bfr[n] = *(const bf16x8*)&Bs[wn * 64 + n * 16 + lr][lk * 8];
#pragma unroll
    for (int m = 0; m < 4; ++m)
#pragma unroll
      for (int n = 0; n < 4; ++n)
        acc[m][n] = __builtin_amdgcn_mfma_f32_16x16x32_bf16(af[m], bfr[n], acc[m][n], 0, 0, 0);
    __syncthreads();
  }
#pragma unroll
  for (int m = 0; m < 4; ++m) {
    int row = trow0 + wm * 64 + m * 16 + lk * 4;
#pragma unroll
    for (int n = 0; n < 4; ++n) {
      int col = ncol0 + wn * 64 + n * 16 + lr;
      float bv = b1[col];
#pragma unroll
      for (int r = 0; r < 4; ++r)
        H[(size_t)(row + r) * FDIM + col] = f2bf(gelu_tanh(acc[m][n][r] + bv));
    }
  }
}

__global__ __launch_bounds__(256)
void g2_old(const unsigned short* __restrict__ H, const float* __restrict__ W2,
            const float* __restrict__ b2, const float* __restrict__ combine,
            int e, float* __restrict__ out) {
  __shared__ unsigned short As[BM][LDT];
  __shared__ unsigned short Bs[BN][LDT];
  int tid = threadIdx.x;
  int trow0 = blockIdx.y * BM, ncol0 = blockIdx.x * BN;
  int wave = tid >> 6, lane = tid & 63;
  int wm = wave >> 1, wn = wave & 1;
  int lr = lane & 15, lk = lane >> 4;
  f32x4 acc[4][4] = {};
  for (int kt = 0; kt < FDIM; kt += BK) {
#pragma unroll
    for (int it = 0; it < 2; ++it) {
      int i = tid + it * 256;
      int row = i >> 2, c8 = (i & 3) << 3;
      uint4 v = *(const uint4*)(H + (size_t)(trow0 + row) * FDIM + kt + c8);
      *(uint4*)&As[row][c8] = v;
    }
#pragma unroll
    for (int it = 0; it < 4; ++it) {
      int i = tid + it * 256;
      int r = i >> 5, c4 = (i & 31) << 2;
      const float4 v = *(const float4*)(W2 + (size_t)(kt + r) * DDIM + ncol0 + c4);
      Bs[c4 + 0][r] = f2bf(v.x); Bs[c4 + 1][r] = f2bf(v.y);
      Bs[c4 + 2][r] = f2bf(v.z); Bs[c4 + 3][r] = f2bf(v.w);
    }
    __syncthreads();
    bf16x8 af[4], bfr[4];
#pragma unroll
    for (int m = 0; m < 4; ++m) af[m] = *(const bf16x8*)&As[wm * 64 + m * 16 + lr][lk * 8];
#pragma unroll
    for (int n = 0; n < 4; ++n) bfr[n] = *(const bf16x8*)&Bs[wn * 64 + n * 16 + lr][lk * 8];
#pragma unroll
    for (int m = 0; m < 4; ++m)
#pragma unroll
      for (int n = 0; n < 4; ++n)
        acc[m][n] = __builtin_amdgcn_mfma_f32_16x16x32_bf16(af[m], bfr[n], acc[m][n], 0, 0, 0);
    __syncthreads();
  }
#pragma unroll
  for (int m = 0; m < 4; ++m) {
    int row = trow0 + wm * 64 + m * 16 + lk * 4;
#pragma unroll
    for (int n = 0; n < 4; ++n) {
      int col = ncol0 + wn * 64 + n * 16 + lr;
      float bv = b2[col];
#pragma unroll
      for (int r = 0; r < 4; ++r) {
        int rr = row + r;
        float c = combine[rr * EEXP + e];
        if (c != 0.0f) out[(size_t)rr * DDIM + col] += c * (acc[m][n][r] + bv);
      }
    }
  }
}

extern "C" void kernel_launch(void* const* d_in, const int* in_sizes, int n_in,
                              void* d_out, int out_size, void* d_ws, size_t ws_size,
                              hipStream_t stream) {
  const float* x     = (const float*)d_in[0];
  const float* Wr    = (const float*)d_in[1];
  const float* br    = (const float*)d_in[2];
  const float* W1    = (const float*)d_in[3];
  const float* b1    = (const float*)d_in[4];
  const float* W2    = (const float*)d_in[5];
  const float* b2    = (const float*)d_in[6];
  const float* gamma = (const float*)d_in[7];
  const float* beta  = (const float*)d_in[8];

  // ws layout: combine | meta | idx | xbf | accum | Hc | W1t | W2t
  size_t off_combine = 0;
  size_t off_meta    = off_combine + (size_t)T_TOK * EEXP * 4;
  size_t off_idx     = off_meta + 1024;
  size_t off_xbf     = off_idx + (size_t)EEXP * T_TOK * 4;
  size_t off_accum   = off_xbf + (size_t)T_TOK * DDIM * 2;
  size_t off_Hc      = off_accum + (size_t)T_TOK * DDIM * 4;
  size_t off_W1t     = off_Hc + (size_t)2 * T_TOK * FDIM * 2;
  size_t off_W2t     = off_W1t + (size_t)EEXP * DDIM * FDIM * 2;
  size_t need        = off_W2t + (size_t)EEXP * DDIM * FDIM * 2;   // ~92.1 MB

  float* combine = (float*)((char*)d_ws + off_combine);

  if (ws_size >= need) {
    int*   meta  = (int*)((char*)d_ws + off_meta);
    int*   idx   = (int*)((char*)d_ws + off_idx);
    unsigned short* xbf = (unsigned short*)((char*)d_ws + off_xbf);
    float* accum = (float*)((char*)d_ws + off_accum);
    unsigned short* Hc  = (unsigned short*)((char*)d_ws + off_Hc);
    unsigned short* W1t = (unsigned short*)((char*)d_ws + off_W1t);
    unsigned short* W2t = (unsigned short*)((char*)d_ws + off_W2t);

    wconv_kernel<<<dim3(2048, 1, 16), 256, 0, stream>>>(W1, W2, W1t, W2t);
    router_kernel<<<T_TOK, 256, 0, stream>>>(x, Wr, br, combine, xbf);
    compact_kernel<<<1, 512, 0, stream>>>(combine, idx, meta);
    hipMemsetAsync(accum, 0, (size_t)T_TOK * DDIM * 4, stream);
    gemm_kernel<0><<<2048, 256, 0, stream>>>(xbf, W1t, b1, combine, idx, meta, Hc, nullptr);
    gemm_kernel<1><<<2048, 256, 0, stream>>>(Hc, W2t, b2, combine, idx, meta, nullptr, accum);
    ln_kernel<<<T_TOK, 256, 0, stream>>>(x, accum, gamma, beta, (float*)d_out);
  } else {
    // proven round-1 path (needs ~16.1 MB ws)
    float* accum = (float*)((char*)d_ws + off_xbf);
    unsigned short* Hbf = (unsigned short*)(accum + (size_t)T_TOK * DDIM);
    hipMemsetAsync(accum, 0, (size_t)T_TOK * DDIM * 4, stream);
    router_kernel<<<T_TOK, 256, 0, stream>>>(x, Wr, br, combine, Hbf /*scratch, unused later*/);
    for (int e = 0; e < EEXP; ++e) {
      g1_old<<<dim3(FDIM / BN, T_TOK / BM), 256, 0, stream>>>(
          x, W1 + (size_t)e * DDIM * FDIM, b1 + (size_t)e * FDIM, Hbf);
      g2_old<<<dim3(DDIM / BN, T_TOK / BM), 256, 0, stream>>>(
          Hbf, W2 + (size_t)e * FDIM * DDIM, b2 + (size_t)e * DDIM, combine, e, accum);
    }
    ln_kernel<<<T_TOK, 256, 0, stream>>>(x, accum, gamma, beta, (float*)d_out);
  }
}

// Round 5
// 309.875 us; speedup vs baseline: 1.1476x; 1.1476x over previous
//
#include <hip/hip_runtime.h>

#define T_TOK 2048
#define DDIM  1024
#define EEXP  8
#define FDIM  2048

typedef __attribute__((ext_vector_type(8))) short bf16x8;
typedef __attribute__((ext_vector_type(4))) float f32x4;
typedef __attribute__((ext_vector_type(4))) unsigned short u16x4;

__device__ __forceinline__ unsigned short f2bf(float f) {
  union { float f; unsigned int u; } v; v.f = f;
  unsigned int r = v.u + 0x7FFF + ((v.u >> 16) & 1);   // RNE
  return (unsigned short)(r >> 16);
}
__device__ __forceinline__ float gelu_tanh(float x) {
  const float c = 0.7978845608028654f;  // sqrt(2/pi)
  float t = c * (x + 0.044715f * x * x * x);
  return 0.5f * x * (1.0f + tanhf(t));
}
__device__ __forceinline__ void gload_lds16(const void* g, void* lds) {
  __builtin_amdgcn_global_load_lds(
      (const __attribute__((address_space(1))) void*)g,
      (__attribute__((address_space(3))) void*)lds, 16, 0, 0);
}

// ---------------- Router (+ fused x -> bf16 convert) ------------------------
__global__ __launch_bounds__(256)
void router_kernel(const float* __restrict__ x, const float* __restrict__ Wr,
                   const float* __restrict__ br, float* __restrict__ combine,
                   unsigned short* __restrict__ xbf) {
  int t = blockIdx.x;
  int tid = threadIdx.x;
  float acc[EEXP];
#pragma unroll
  for (int e = 0; e < EEXP; ++e) acc[e] = 0.f;
  const float* xr = x + (size_t)t * DDIM;
  unsigned short* xbr = xbf + (size_t)t * DDIM;
  for (int d = tid; d < DDIM; d += 256) {
    float xv = xr[d];
    xbr[d] = f2bf(xv);
    const float* w = Wr + d * EEXP;
#pragma unroll
    for (int e = 0; e < EEXP; ++e) acc[e] += xv * w[e];
  }
#pragma unroll
  for (int e = 0; e < EEXP; ++e)
    for (int off = 32; off > 0; off >>= 1) acc[e] += __shfl_down(acc[e], off);
  __shared__ float red[4][EEXP];
  int wave = tid >> 6, lane = tid & 63;
  if (lane == 0)
#pragma unroll
    for (int e = 0; e < EEXP; ++e) red[wave][e] = acc[e];
  __syncthreads();
  if (tid == 0) {
    float l[EEXP];
#pragma unroll
    for (int e = 0; e < EEXP; ++e)
      l[e] = red[0][e] + red[1][e] + red[2][e] + red[3][e] + br[e];
    int i0 = 0;
    for (int e = 1; e < EEXP; ++e) if (l[e] > l[i0]) i0 = e;
    int i1 = -1;
    for (int e = 0; e < EEXP; ++e) {
      if (e == i0) continue;
      if (i1 < 0 || l[e] > l[i1]) i1 = e;
    }
    float m = l[0];
    for (int e = 1; e < EEXP; ++e) m = fmaxf(m, l[e]);
    float p[EEXP], s = 0.f;
#pragma unroll
    for (int e = 0; e < EEXP; ++e) { p[e] = __expf(l[e] - m); s += p[e]; }
    float inv = 1.0f / s;
#pragma unroll
    for (int e = 0; e < EEXP; ++e)
      combine[t * EEXP + e] = (e == i0 || e == i1) ? p[e] * inv : 0.0f;
  }
}

// ---------------- Compaction: token lists + slot/tile prefixes --------------
// meta[0..7]=counts  [8..15]=row prefix  [16]=total rows
// [17]=total 64-row tiles  [24..31]=tile prefix (exclusive)
__global__ __launch_bounds__(512)
void compact_kernel(const float* __restrict__ combine, int* __restrict__ idx,
                    int* __restrict__ meta) {
  int e = threadIdx.x >> 6, lane = threadIdx.x & 63;
  int cnt = 0;
  for (int t0 = 0; t0 < T_TOK; t0 += 64) {
    int t = t0 + lane;
    bool f = combine[t * EEXP + e] != 0.0f;
    unsigned long long m = __ballot(f);
    if (f) idx[e * T_TOK + cnt + __popcll(m & ((1ull << lane) - 1))] = t;
    cnt += __popcll(m);
  }
  __shared__ int sc[EEXP];
  if (lane == 0) sc[e] = cnt;
  __syncthreads();
  if (threadIdx.x == 0) {
    int b = 0, tb = 0;
    for (int i = 0; i < EEXP; ++i) {
      meta[i] = sc[i]; meta[8 + i] = b; meta[24 + i] = tb;
      b += sc[i]; tb += (sc[i] + 63) >> 6;
    }
    meta[16] = b; meta[17] = tb;
  }
}

// ---------------- Weight transpose+convert: fp32 [R][C] -> bf16 [C][R] ------
__global__ __launch_bounds__(256)
void wconv_kernel(const float* __restrict__ W1, const float* __restrict__ W2,
                  unsigned short* __restrict__ W1t, unsigned short* __restrict__ W2t) {
  __shared__ float tile[32][33];
  int z = blockIdx.z;
  const float* in; unsigned short* out; int R, C;
  if (z < 8) { in = W1 + (size_t)z * DDIM * FDIM; out = W1t + (size_t)z * DDIM * FDIM; R = DDIM; C = FDIM; }
  else       { in = W2 + (size_t)(z - 8) * DDIM * FDIM; out = W2t + (size_t)(z - 8) * DDIM * FDIM; R = FDIM; C = DDIM; }
  int tilesC = C >> 5;
  int tr = blockIdx.x / tilesC, tc = blockIdx.x % tilesC;
  int r0 = tr << 5, c0 = tc << 5;
  int t = threadIdx.x;
  int lr = t >> 3, lc4 = (t & 7) << 2;
  const float4 v = *(const float4*)(in + (size_t)(r0 + lr) * C + c0 + lc4);
  tile[lr][lc4 + 0] = v.x; tile[lr][lc4 + 1] = v.y;
  tile[lr][lc4 + 2] = v.z; tile[lr][lc4 + 3] = v.w;
  __syncthreads();
  u16x4 o;
  o[0] = f2bf(tile[lc4 + 0][lr]);
  o[1] = f2bf(tile[lc4 + 1][lr]);
  o[2] = f2bf(tile[lc4 + 2][lr]);
  o[3] = f2bf(tile[lc4 + 3][lr]);
  *(u16x4*)(out + (size_t)(c0 + lr) * R + r0 + lc4) = o;
}

// ---------------- Dense-active tiled GEMM (BM=64, single-buffer) ------------
// Tile map: tile -> (expert e, local row m0) via meta tile-prefix.
// EPI 0: sub = n-tile (16x128);  Hc[base+l] = gelu(A@B^T + b1)
// EPI 1: sub = (n-tile<<1)|khalf (8x128, split-K 2x1024); accum += c*(A@B^T[+b2])
template<int EPI>
__global__ __launch_bounds__(256)
void gemm_kernel(const unsigned short* __restrict__ A,
                 const unsigned short* __restrict__ Ball,
                 const float* __restrict__ ball,
                 const float* __restrict__ combine,
                 const int* __restrict__ idx,
                 const int* __restrict__ meta,
                 unsigned short* __restrict__ Hc,
                 float* __restrict__ accum) {
  constexpr int KF = (EPI == 0) ? DDIM : FDIM;
  constexpr int N  = (EPI == 0) ? FDIM : DDIM;
  constexpr int NT = 16;                        // 16 x 64 = 1024 K per block
  __shared__ unsigned short Asub[64 * 64];      // 8 KB, swizzled 128B rows
  __shared__ unsigned short Bsub[128 * 64];     // 16 KB

  int id = blockIdx.x;
  int tile = id >> 4, sub = id & 15;
  if (tile >= meta[17]) return;                 // dense-active early exit
  int e = 0;
#pragma unroll
  for (int i = 1; i < 8; ++i) if (tile >= meta[24 + i]) e = i;
  int m0 = (tile - meta[24 + e]) << 6;
  int cnt = meta[e];
  int base = meta[8 + e];
  int n0, kbeg;
  if (EPI == 0) { n0 = sub << 7; kbeg = 0; }
  else          { n0 = (sub >> 1) << 7; kbeg = (sub & 1) << 10; }

  const unsigned short* B = Ball + (size_t)e * KF * N;
  const float* bias = ball + (size_t)e * N;
  int tid = threadIdx.x, wave = tid >> 6, lane = tid & 63;
  int wm = wave >> 1, wn = wave & 1;
  int lr = lane & 15, lk = lane >> 4;

  // staging geometry (loop-invariant; swizzle: byte col2 ^ ((row&7)<<4))
  int arow[2], scolA[2], brow[4], scolB[4];
#pragma unroll
  for (int i = 0; i < 2; ++i) {
    int phys = i * 4096 + wave * 1024 + lane * 16;
    int row = phys >> 7;
    int lc = (phys & 127) ^ ((row & 7) << 4);
    scolA[i] = lc >> 1;
    int lrow = min(m0 + row, cnt - 1);          // clamp ragged tail
    arow[i] = (EPI == 0) ? idx[e * T_TOK + lrow] : (base + lrow);
  }
#pragma unroll
  for (int i = 0; i < 4; ++i) {
    int phys = i * 4096 + wave * 1024 + lane * 16;
    int row = phys >> 7;
    int lc = (phys & 127) ^ ((row & 7) << 4);
    scolB[i] = lc >> 1;
    brow[i] = n0 + row;
  }

  f32x4 acc[2][4] = {};
  for (int t = 0; t < NT; ++t) {
    int kt = kbeg + t * 64;
#pragma unroll
    for (int i = 0; i < 2; ++i)
      gload_lds16(A + (size_t)arow[i] * KF + kt + scolA[i],
                  (char*)Asub + i * 4096 + wave * 1024);
#pragma unroll
    for (int i = 0; i < 4; ++i)
      gload_lds16(B + (size_t)brow[i] * KF + kt + scolB[i],
                  (char*)Bsub + i * 4096 + wave * 1024);
    __syncthreads();
#pragma unroll
    for (int ks = 0; ks < 2; ++ks) {
      bf16x8 af[2], bf_[4];
#pragma unroll
      for (int m = 0; m < 2; ++m) {
        int row = wm * 32 + m * 16 + lr;
        int cb = (ks * 64 + lk * 16) ^ ((row & 7) << 4);
        af[m] = *(const bf16x8*)((const char*)Asub + row * 128 + cb);
      }
#pragma unroll
      for (int n = 0; n < 4; ++n) {
        int row = wn * 64 + n * 16 + lr;
        int cb = (ks * 64 + lk * 16) ^ ((row & 7) << 4);
        bf_[n] = *(const bf16x8*)((const char*)Bsub + row * 128 + cb);
      }
#pragma unroll
      for (int m = 0; m < 2; ++m)
#pragma unroll
        for (int n = 0; n < 4; ++n)
          acc[m][n] = __builtin_amdgcn_mfma_f32_16x16x32_bf16(af[m], bf_[n], acc[m][n], 0, 0, 0);
    }
    __syncthreads();
  }

  if (EPI == 0) {
#pragma unroll
    for (int m = 0; m < 2; ++m) {
      int lbase = m0 + wm * 32 + m * 16 + lk * 4;
#pragma unroll
      for (int n = 0; n < 4; ++n) {
        int col = n0 + wn * 64 + n * 16 + lr;
        float bv = bias[col];
#pragma unroll
        for (int r = 0; r < 4; ++r) {
          int local = lbase + r;
          if (local < cnt)
            Hc[(size_t)(base + local) * N + col] = f2bf(gelu_tanh(acc[m][n][r] + bv));
        }
      }
    }
  } else {
    bool addb = (kbeg == 0);
#pragma unroll
    for (int m = 0; m < 2; ++m) {
      int lbase = m0 + wm * 32 + m * 16 + lk * 4;
#pragma unroll
      for (int r = 0; r < 4; ++r) {
        int local = lbase + r;
        if (local < cnt) {
          int tok = idx[e * T_TOK + local];
          float c = combine[tok * EEXP + e];
#pragma unroll
          for (int n = 0; n < 4; ++n) {
            int col = n0 + wn * 64 + n * 16 + lr;
            float v = acc[m][n][r] + (addb ? bias[col] : 0.0f);
            atomicAdd(&accum[(size_t)tok * N + col], c * v);
          }
        }
      }
    }
  }
}

// ---------------- Residual + LayerNorm --------------------------------------
__global__ __launch_bounds__(256)
void ln_kernel(const float* __restrict__ x, const float* __restrict__ accum,
               const float* __restrict__ gamma, const float* __restrict__ beta,
               float* __restrict__ out) {
  int r = blockIdx.x, tid = threadIdx.x;
  size_t base = (size_t)r * DDIM + tid * 4;
  float4 xv = *(const float4*)(x + base);
  float4 av = *(const float4*)(accum + base);
  float y[4] = { xv.x + av.x, xv.y + av.y, xv.z + av.z, xv.w + av.w };
  float s = y[0] + y[1] + y[2] + y[3];
  float s2 = y[0] * y[0] + y[1] * y[1] + y[2] * y[2] + y[3] * y[3];
  for (int off = 32; off > 0; off >>= 1) {
    s += __shfl_down(s, off);
    s2 += __shfl_down(s2, off);
  }
  __shared__ float rs[4], rs2[4];
  int wave = tid >> 6, lane = tid & 63;
  if (lane == 0) { rs[wave] = s; rs2[wave] = s2; }
  __syncthreads();
  float ts = rs[0] + rs[1] + rs[2] + rs[3];
  float ts2 = rs2[0] + rs2[1] + rs2[2] + rs2[3];
  float mu = ts * (1.0f / DDIM);
  float var = ts2 * (1.0f / DDIM) - mu * mu;
  float inv = rsqrtf(var + 1e-5f);
  float4 gv = *(const float4*)(gamma + tid * 4);
  float4 bv = *(const float4*)(beta + tid * 4);
  float4 o;
  o.x = (y[0] - mu) * inv * gv.x + bv.x;
  o.y = (y[1] - mu) * inv * gv.y + bv.y;
  o.z = (y[2] - mu) * inv * gv.z + bv.z;
  o.w = (y[3] - mu) * inv * gv.w + bv.w;
  *(float4*)(out + base) = o;
}

// ================= FALLBACK (round-1 proven path, small ws) =================
#define BM 128
#define BN 128
#define BK 32
#define LDT 40

__global__ __launch_bounds__(256)
void g1_old(const float* __restrict__ X, const float* __restrict__ W1,
            const float* __restrict__ b1, unsigned short* __restrict__ H) {
  __shared__ unsigned short As[BM][LDT];
  __shared__ unsigned short Bs[BN][LDT];
  int tid = threadIdx.x;
  int trow0 = blockIdx.y * BM, ncol0 = blockIdx.x * BN;
  int wave = tid >> 6, lane = tid & 63;
  int wm = wave >> 1, wn = wave & 1;
  int lr = lane & 15, lk = lane >> 4;
  f32x4 acc[4][4] = {};
  for (int kt = 0; kt < DDIM; kt += BK) {
#pragma unroll
    for (int it = 0; it < 4; ++it) {
      int i = tid + it * 256;
      int row = i >> 3, c4 = (i & 7) << 2;
      const float4 v = *(const float4*)(X + (size_t)(trow0 + row) * DDIM + kt + c4);
      uint2 p;
      p.x = (unsigned int)f2bf(v.x) | ((unsigned int)f2bf(v.y) << 16);
      p.y = (unsigned int)f2bf(v.z) | ((unsigned int)f2bf(v.w) << 16);
      *(uint2*)&As[row][c4] = p;
    }
#pragma unroll
    for (int it = 0; it < 4; ++it) {
      int i = tid + it * 256;
      int r = i >> 5, c4 = (i & 31) << 2;
      const float4 v = *(const float4*)(W1 + (size_t)(kt + r) * FDIM + ncol0 + c4);
      Bs[c4 + 0][r] = f2bf(v.x); Bs[c4 + 1][r] = f2bf(v.y);
      Bs[c4 + 2][r] = f2bf(v.z); Bs[c4 + 3][r] = f2bf(v.w);
    }
    __syncthreads();
    bf16x8 af[4], bfr[4];
#pragma unroll
    for (int m = 0; m < 4; ++m) af[m] = *(const bf16x8*)&As[wm * 64 + m * 16 + lr][lk * 8];
#pragma unroll
    for (int n = 0; n < 4; ++n) bfr[n] = *(const bf16x8*)&Bs[wn * 64 + n * 16 + lr][lk * 8];
#pragma unroll
    for (int m = 0; m < 4; ++m)
#pragma unroll
      for (int n = 0; n < 4; ++n)
        acc[m][n] = __builtin_amdgcn_mfma_f32_16x16x32_bf16(af[m], bfr[n], acc[m][n], 0, 0, 0);
    __syncthreads();
  }
#pragma unroll
  for (int m = 0; m < 4; ++m) {
    int row = trow0 + wm * 64 + m * 16 + lk * 4;
#pragma unroll
    for (int n = 0; n < 4; ++n) {
      int col = ncol0 + wn * 64 + n * 16 + lr;
      float bv = b1[col];
#pragma unroll
      for (int r = 0; r < 4; ++r)
        H[(size_t)(row + r) * FDIM + col] = f2bf(gelu_tanh(acc[m][n][r] + bv));
    }
  }
}

__global__ __launch_bounds__(256)
void g2_old(const unsigned short* __restrict__ H, const float* __restrict__ W2,
            const float* __restrict__ b2, const float* __restrict__ combine,
            int e, float* __restrict__ out) {
  __shared__ unsigned short As[BM][LDT];
  __shared__ unsigned short Bs[BN][LDT];
  int tid = threadIdx.x;
  int trow0 = blockIdx.y * BM, ncol0 = blockIdx.x * BN;
  int wave = tid >> 6, lane = tid & 63;
  int wm = wave >> 1, wn = wave & 1;
  int lr = lane & 15, lk = lane >> 4;
  f32x4 acc[4][4] = {};
  for (int kt = 0; kt < FDIM; kt += BK) {
#pragma unroll
    for (int it = 0; it < 2; ++it) {
      int i = tid + it * 256;
      int row = i >> 2, c8 = (i & 3) << 3;
      uint4 v = *(const uint4*)(H + (size_t)(trow0 + row) * FDIM + kt + c8);
      *(uint4*)&As[row][c8] = v;
    }
#pragma unroll
    for (int it = 0; it < 4; ++it) {
      int i = tid + it * 256;
      int r = i >> 5, c4 = (i & 31) << 2;
      const float4 v = *(const float4*)(W2 + (size_t)(kt + r) * DDIM + ncol0 + c4);
      Bs[c4 + 0][r] = f2bf(v.x); Bs[c4 + 1][r] = f2bf(v.y);
      Bs[c4 + 2][r] = f2bf(v.z); Bs[c4 + 3][r] = f2bf(v.w);
    }
    __syncthreads();
    bf16x8 af[4], bfr[4];
#pragma unroll
    for (int m = 0; m < 4; ++m) af[m] = *(const bf16x8*)&As[wm * 64 + m * 16 + lr][lk * 8];
#pragma unroll
    for (int n = 0; n < 4; ++n) bfr[n] = *(const bf16x8*)&Bs[wn * 64 + n * 16 + lr][lk * 8];
#pragma unroll
    for (int m = 0; m < 4; ++m)
#pragma unroll
      for (int n = 0; n < 4; ++n)
        acc[m][n] = __builtin_amdgcn_mfma_f32_16x16x32_bf16(af[m], bfr[n], acc[m][n], 0, 0, 0);
    __syncthreads();
  }
#pragma unroll
  for (int m = 0; m < 4; ++m) {
    int row = trow0 + wm * 64 + m * 16 + lk * 4;
#pragma unroll
    for (int n = 0; n < 4; ++n) {
      int col = ncol0 + wn * 64 + n * 16 + lr;
      float bv = b2[col];
#pragma unroll
      for (int r = 0; r < 4; ++r) {
        int rr = row + r;
        float c = combine[rr * EEXP + e];
        if (c != 0.0f) out[(size_t)rr * DDIM + col] += c * (acc[m][n][r] + bv);
      }
    }
  }
}

extern "C" void kernel_launch(void* const* d_in, const int* in_sizes, int n_in,
                              void* d_out, int out_size, void* d_ws, size_t ws_size,
                              hipStream_t stream) {
  const float* x     = (const float*)d_in[0];
  const float* Wr    = (const float*)d_in[1];
  const float* br    = (const float*)d_in[2];
  const float* W1    = (const float*)d_in[3];
  const float* b1    = (const float*)d_in[4];
  const float* W2    = (const float*)d_in[5];
  const float* b2    = (const float*)d_in[6];
  const float* gamma = (const float*)d_in[7];
  const float* beta  = (const float*)d_in[8];

  // ws layout: combine | meta | idx | xbf | accum | Hc | W1t | W2t
  size_t off_combine = 0;
  size_t off_meta    = off_combine + (size_t)T_TOK * EEXP * 4;
  size_t off_idx     = off_meta + 1024;
  size_t off_xbf     = off_idx + (size_t)EEXP * T_TOK * 4;
  size_t off_accum   = off_xbf + (size_t)T_TOK * DDIM * 2;
  size_t off_Hc      = off_accum + (size_t)T_TOK * DDIM * 4;
  size_t off_W1t     = off_Hc + (size_t)2 * T_TOK * FDIM * 2;
  size_t off_W2t     = off_W1t + (size_t)EEXP * DDIM * FDIM * 2;
  size_t need        = off_W2t + (size_t)EEXP * DDIM * FDIM * 2;   // ~92.1 MB

  float* combine = (float*)((char*)d_ws + off_combine);

  if (ws_size >= need) {
    int*   meta  = (int*)((char*)d_ws + off_meta);
    int*   idx   = (int*)((char*)d_ws + off_idx);
    unsigned short* xbf = (unsigned short*)((char*)d_ws + off_xbf);
    float* accum = (float*)((char*)d_ws + off_accum);
    unsigned short* Hc  = (unsigned short*)((char*)d_ws + off_Hc);
    unsigned short* W1t = (unsigned short*)((char*)d_ws + off_W1t);
    unsigned short* W2t = (unsigned short*)((char*)d_ws + off_W2t);

    wconv_kernel<<<dim3(2048, 1, 16), 256, 0, stream>>>(W1, W2, W1t, W2t);
    router_kernel<<<T_TOK, 256, 0, stream>>>(x, Wr, br, combine, xbf);
    compact_kernel<<<1, 512, 0, stream>>>(combine, idx, meta);
    hipMemsetAsync(accum, 0, (size_t)T_TOK * DDIM * 4, stream);
    // 72 = max 64-row tiles (sum ceil(cnt_e/64) <= 4096/64 + 8)
    gemm_kernel<0><<<72 * 16, 256, 0, stream>>>(xbf, W1t, b1, combine, idx, meta, Hc, nullptr);
    gemm_kernel<1><<<72 * 16, 256, 0, stream>>>(Hc, W2t, b2, combine, idx, meta, nullptr, accum);
    ln_kernel<<<T_TOK, 256, 0, stream>>>(x, accum, gamma, beta, (float*)d_out);
  } else {
    // proven round-1 path (needs ~16.1 MB ws)
    float* accum = (float*)((char*)d_ws + off_xbf);
    unsigned short* Hbf = (unsigned short*)(accum + (size_t)T_TOK * DDIM);
    hipMemsetAsync(accum, 0, (size_t)T_TOK * DDIM * 4, stream);
    router_kernel<<<T_TOK, 256, 0, stream>>>(x, Wr, br, combine, Hbf /*scratch*/);
    for (int e = 0; e < EEXP; ++e) {
      g1_old<<<dim3(FDIM / BN, T_TOK / BM), 256, 0, stream>>>(
          x, W1 + (size_t)e * DDIM * FDIM, b1 + (size_t)e * FDIM, Hbf);
      g2_old<<<dim3(DDIM / BN, T_TOK / BM), 256, 0, stream>>>(
          Hbf, W2 + (size_t)e * FDIM * DDIM, b2 + (size_t)e * DDIM, combine, e, accum);
    }
    ln_kernel<<<T_TOK, 256, 0, stream>>>(x, accum, gamma, beta, (float*)d_out);
  }
}